// Round 6
// baseline (180.507 us; speedup 1.0000x reference)
//
#include <hip/hip_runtime.h>

#define BATCH   32768
#define SD      256
#define LD      64
#define HDIM    64
#define NEMB    2048
#define REFINE_THR_Q 5e-4f   // gap in q-units; s-gap = 2*q-gap -> 1e-3 effective

typedef short  short8 __attribute__((ext_vector_type(8)));
typedef float  f32x4  __attribute__((ext_vector_type(4)));

// bf16 RNE helpers (bit ops, finite data)
__device__ __forceinline__ unsigned short f2bf(float f) {
    unsigned int u = __float_as_uint(f);
    u = (u + 0x7FFFu + ((u >> 16) & 1u)) >> 16;
    return (unsigned short)u;
}
__device__ __forceinline__ float bf2f(unsigned short h) {
    return __uint_as_float(((unsigned int)h) << 16);
}

// ---------------------------------------------------------------------------
// K0: e2q[k] = -0.5*||emb[k]||^2 (MFMA C-init), bf16 split eh/el, zero counter.
// ---------------------------------------------------------------------------
__global__ __launch_bounds__(256) void k0_prep(const float* __restrict__ emb,
                                               float* __restrict__ e2q,
                                               unsigned short* __restrict__ eh,
                                               unsigned short* __restrict__ el,
                                               int* __restrict__ count) {
    int k = blockIdx.x * 256 + threadIdx.x;
    if (k == 0) *count = 0;
    const float* er = emb + (size_t)k * LD;
    unsigned short hrow[LD], lrow[LD];
    float s = 0.f;
#pragma unroll
    for (int q = 0; q < LD; ++q) {
        float v = er[q];
        s += v * v;
        unsigned short h = f2bf(v);
        hrow[q] = h;
        lrow[q] = f2bf(v - bf2f(h));
    }
    e2q[k] = -0.5f * s;
    short8* dh = (short8*)(eh + (size_t)k * LD);
    short8* dl = (short8*)(el + (size_t)k * LD);
#pragma unroll
    for (int q = 0; q < 8; ++q) {
        dh[q] = *(short8*)&hrow[q * 8];
        dl[q] = *(short8*)&lrow[q * 8];
    }
}

// ---------------------------------------------------------------------------
// K1a: h = relu(x @ enc_w1 + enc_b1)  (proven fast round 4/5)
// ---------------------------------------------------------------------------
__global__ __launch_bounds__(512, 4) void k1a_enc1(const float* __restrict__ x,
                                                   const float* __restrict__ w1,
                                                   const float* __restrict__ b1,
                                                   float* __restrict__ hOut) {
    __shared__ float w1s[SD * HDIM];       // 64 KB
    __shared__ float xs[2][64 * 32];       // 16 KB
    int tid = threadIdx.x;
    {
        const float4* src = (const float4*)w1;
        float4* dst = (float4*)w1s;
#pragma unroll
        for (int t = 0; t < 8; ++t) dst[tid + 512 * t] = src[tid + 512 * t];
    }
    int r0 = blockIdx.x * 64;
    int sr = tid >> 3;
    int sq = tid & 7;
    const float* xrow = x + (size_t)(r0 + sr) * SD + sq * 4;

    {
        float4 v = *(const float4*)xrow;
        *(float4*)&xs[0][sr * 32 + sq * 4] = v;
    }
    __syncthreads();

    int lane = tid & 63;
    int w = tid >> 6;
    float acc[8];
#pragma unroll
    for (int r = 0; r < 8; ++r) acc[r] = 0.f;

    for (int c = 0; c < 8; ++c) {
        float4 nv;
        if (c < 7) nv = *(const float4*)(xrow + (c + 1) * 32);
        const float* xb = &xs[c & 1][(w * 8) * 32];
        int kb = c * 32;
#pragma unroll
        for (int i0 = 0; i0 < 32; i0 += 8) {
            float wf[8];
#pragma unroll
            for (int jj = 0; jj < 8; ++jj) wf[jj] = w1s[(kb + i0 + jj) * HDIM + lane];
#pragma unroll
            for (int r = 0; r < 8; ++r) {
                const float* xr = xb + r * 32 + i0;
                float4 xa = *(const float4*)xr;
                float4 xc = *(const float4*)(xr + 4);
                acc[r] += xa.x * wf[0] + xa.y * wf[1] + xa.z * wf[2] + xa.w * wf[3]
                        + xc.x * wf[4] + xc.y * wf[5] + xc.z * wf[6] + xc.w * wf[7];
            }
        }
        __syncthreads();
        if (c < 7) *(float4*)&xs[(c + 1) & 1][sr * 32 + sq * 4] = nv;
        __syncthreads();
    }
    float bb = b1[lane];
#pragma unroll
    for (int r = 0; r < 8; ++r) {
        float h = acc[r] + bb;
        hOut[(size_t)(r0 + w * 8 + r) * HDIM + lane] = fmaxf(h, 0.f);
    }
}

// ---------------------------------------------------------------------------
// K1b: z_e = h @ enc_w2 + enc_b2, fused bf16 split z -> zh, zl
// ---------------------------------------------------------------------------
__global__ __launch_bounds__(512, 4) void k1b_enc2(const float* __restrict__ hIn,
                                                   const float* __restrict__ w2,
                                                   const float* __restrict__ b2,
                                                   float* __restrict__ zOut,
                                                   unsigned short* __restrict__ zh,
                                                   unsigned short* __restrict__ zl) {
    __shared__ float w2s[HDIM * LD];   // 16 KB
    __shared__ float hs[64 * 64];      // 16 KB
    int tid = threadIdx.x;
    {
        const float4* src = (const float4*)w2;
        float4* dst = (float4*)w2s;
        dst[tid] = src[tid];
        dst[tid + 512] = src[tid + 512];
    }
    int r0 = blockIdx.x * 64;
    {
        const float4* src = (const float4*)(hIn + (size_t)r0 * HDIM);
        float4* dst = (float4*)hs;
        dst[tid] = src[tid];
        dst[tid + 512] = src[tid + 512];
    }
    __syncthreads();

    int lane = tid & 63;
    int w = tid >> 6;
    const float* hb = &hs[(w * 8) * 64];

    float acc[8];
#pragma unroll
    for (int r = 0; r < 8; ++r) acc[r] = 0.f;

    for (int j0 = 0; j0 < HDIM; j0 += 8) {
        float wf[8];
#pragma unroll
        for (int jj = 0; jj < 8; ++jj) wf[jj] = w2s[(j0 + jj) * LD + lane];
#pragma unroll
        for (int r = 0; r < 8; ++r) {
            const float* hr = hb + r * 64 + j0;
            float4 ha = *(const float4*)hr;
            float4 hc = *(const float4*)(hr + 4);
            acc[r] += ha.x * wf[0] + ha.y * wf[1] + ha.z * wf[2] + ha.w * wf[3]
                    + hc.x * wf[4] + hc.y * wf[5] + hc.z * wf[6] + hc.w * wf[7];
        }
    }
    float bb = b2[lane];
#pragma unroll
    for (int r = 0; r < 8; ++r) {
        float z = acc[r] + bb;
        size_t o = (size_t)(r0 + w * 8 + r) * LD + lane;
        zOut[o] = z;
        unsigned short h = f2bf(z);
        zh[o] = h;
        zl[o] = f2bf(z - bf2f(h));
    }
}

// ---------------------------------------------------------------------------
// K2: MFMA split-bf16 screen, max-form.  q = z.e - 0.5||e||^2 (C-init = e2q).
// 1024 blocks x 256 thr: 32 rows/block, wave = quarter codebook (512 codes).
// 4 blocks/CU -> 16 waves/CU for MFMA||VALU overlap.
// C layout (m89): col = lane&15 = batch row, row = (lane>>4)*4+reg = code.
// ---------------------------------------------------------------------------
__global__ __launch_bounds__(256, 4) void k2_mfma(const unsigned short* __restrict__ zh,
                                                  const unsigned short* __restrict__ zl,
                                                  const unsigned short* __restrict__ eh,
                                                  const unsigned short* __restrict__ el,
                                                  const float* __restrict__ e2q,
                                                  int* __restrict__ idx,
                                                  int* __restrict__ list,
                                                  int* __restrict__ count) {
    int tid  = threadIdx.x;
    int lane = tid & 63;
    int w    = tid >> 6;           // wave -> code quarter
    int rb   = blockIdx.x * 32;    // 32 batch rows per block
    int lo   = lane & 15;
    int hi   = lane >> 4;

    short8 bh[2][2], bl[2][2];
#pragma unroll
    for (int g = 0; g < 2; ++g) {
        size_t zo = (size_t)(rb + g * 16 + lo) * LD + hi * 8;
        bh[g][0] = *(const short8*)(zh + zo);
        bh[g][1] = *(const short8*)(zh + zo + 32);
        bl[g][0] = *(const short8*)(zl + zo);
        bl[g][1] = *(const short8*)(zl + zo + 32);
    }

    float bb[2], ss[2];
    int   ii[2];
#pragma unroll
    for (int g = 0; g < 2; ++g) { bb[g] = -3.0e38f; ss[g] = -3.0e38f; ii[g] = 0; }

    const int cbase = w * (NEMB / 4);
    const unsigned short* ehp = eh + (size_t)(cbase + lo) * LD + hi * 8;
    const unsigned short* elp = el + (size_t)(cbase + lo) * LD + hi * 8;

    short8 a0 = *(const short8*)(ehp);
    short8 a1 = *(const short8*)(ehp + 32);
    short8 a2 = *(const short8*)(elp);
    short8 a3 = *(const short8*)(elp + 32);
    f32x4 e2c = *(const f32x4*)(e2q + cbase + hi * 4);

    for (int t = 0; t < NEMB / 4 / 16; ++t) {
        short8 n0 = a0, n1 = a1, n2 = a2, n3 = a3;
        f32x4 e2n = e2c;
        if (t < NEMB / 4 / 16 - 1) {
            const unsigned short* ph = ehp + (size_t)(t + 1) * 16 * LD;
            const unsigned short* pl = elp + (size_t)(t + 1) * 16 * LD;
            n0 = *(const short8*)(ph);
            n1 = *(const short8*)(ph + 32);
            n2 = *(const short8*)(pl);
            n3 = *(const short8*)(pl + 32);
            e2n = *(const f32x4*)(e2q + cbase + (t + 1) * 16 + hi * 4);
        }

        f32x4 acc[2];
#pragma unroll
        for (int g = 0; g < 2; ++g) {
            f32x4 c;
            c = __builtin_amdgcn_mfma_f32_16x16x32_bf16(a0, bh[g][0], e2c, 0, 0, 0);
            c = __builtin_amdgcn_mfma_f32_16x16x32_bf16(a1, bh[g][1], c, 0, 0, 0);
            c = __builtin_amdgcn_mfma_f32_16x16x32_bf16(a2, bh[g][0], c, 0, 0, 0);
            c = __builtin_amdgcn_mfma_f32_16x16x32_bf16(a3, bh[g][1], c, 0, 0, 0);
            c = __builtin_amdgcn_mfma_f32_16x16x32_bf16(a0, bl[g][0], c, 0, 0, 0);
            c = __builtin_amdgcn_mfma_f32_16x16x32_bf16(a1, bl[g][1], c, 0, 0, 0);
            acc[g] = c;
        }

        int base4 = cbase + t * 16 + hi * 4;
#pragma unroll
        for (int g = 0; g < 2; ++g) {
            float s0 = acc[g][0], s1 = acc[g][1], s2 = acc[g][2], s3 = acc[g][3];
            float M01 = fmaxf(s0, s1), L01 = fminf(s0, s1);
            float M23 = fmaxf(s2, s3), L23 = fminf(s2, s3);
            int   d01 = (s1 > s0) ? 1 : 0;
            int   d23 = (s3 > s2) ? 3 : 2;
            bool  cp  = (M23 > M01);
            float m   = fmaxf(M01, M23);
            float mn  = fminf(M01, M23);
            int   d   = cp ? d23 : d01;
            float hw  = cp ? L23 : L01;
            float t2  = fmaxf(mn, hw);
            ii[g] = (m > bb[g]) ? (base4 + d) : ii[g];
            ss[g] = fmaxf(fmaxf(fminf(bb[g], m), t2), ss[g]);
            bb[g] = fmaxf(bb[g], m);
        }

        a0 = n0; a1 = n1; a2 = n2; a3 = n3; e2c = e2n;
    }

    // cross-lane merge over hi (lanes c, c+16, c+32, c+48)
#pragma unroll
    for (int off = 16; off <= 32; off <<= 1) {
#pragma unroll
        for (int g = 0; g < 2; ++g) {
            float ob = __shfl_xor(bb[g], off);
            float os = __shfl_xor(ss[g], off);
            int   oi = __shfl_xor(ii[g], off);
            ss[g] = fmaxf(fmaxf(fminf(bb[g], ob), os), ss[g]);
            ii[g] = (ob > bb[g]) ? oi : ii[g];
            bb[g] = fmaxf(bb[g], ob);
        }
    }

    // cross-wave merge (4 code quarters) via LDS
    __shared__ float Lb[4][32];
    __shared__ float Ls[4][32];
    __shared__ int   Li[4][32];
    if (lane < 16) {
#pragma unroll
        for (int g = 0; g < 2; ++g) {
            Lb[w][g * 16 + lane] = bb[g];
            Ls[w][g * 16 + lane] = ss[g];
            Li[w][g * 16 + lane] = ii[g];
        }
    }
    __syncthreads();

    if (tid < 32) {
        float B = Lb[0][tid], S = Ls[0][tid];
        int   I = Li[0][tid];
#pragma unroll
        for (int w2 = 1; w2 < 4; ++w2) {
            float ob = Lb[w2][tid], os = Ls[w2][tid];
            int   oi = Li[w2][tid];
            S = fmaxf(fmaxf(fminf(B, ob), os), S);
            I = (ob > B) ? oi : I;
            B = fmaxf(B, ob);
        }
        idx[rb + tid] = I;
        if (B - S < REFINE_THR_Q) {
            int p = atomicAdd(count, 1);
            list[p] = rb + tid;
        }
    }
}

// ---------------------------------------------------------------------------
// K3: exact f64 rescan of flagged near-tie rows.
// ---------------------------------------------------------------------------
__global__ __launch_bounds__(256) void k3_refine(const float* __restrict__ z,
                                                 const float* __restrict__ emb,
                                                 const int* __restrict__ count,
                                                 const int* __restrict__ list,
                                                 int* __restrict__ idx) {
    __shared__ double sv[256];
    __shared__ int    sx[256];
    int tid = threadIdx.x;
    int n = *count;
    for (int g = blockIdx.x; g < n; g += gridDim.x) {
        int row = list[g];
        const float4* zr4 = (const float4*)(z + (size_t)row * LD);
        float4 zv[16];
#pragma unroll
        for (int q = 0; q < 16; ++q) zv[q] = zr4[q];

        double best = 1.0e300;
        int bi = NEMB;
#pragma unroll 2
        for (int c = 0; c < 8; ++c) {
            int k = tid * 8 + c;
            const float4* er = (const float4*)(emb + (size_t)k * LD);
            double d0 = 0.0, d1 = 0.0, d2 = 0.0, d3 = 0.0;
#pragma unroll
            for (int q = 0; q < 16; ++q) {
                float4 e4 = er[q];
                double tx = (double)zv[q].x - (double)e4.x;
                double ty = (double)zv[q].y - (double)e4.y;
                double tz = (double)zv[q].z - (double)e4.z;
                double tw = (double)zv[q].w - (double)e4.w;
                d0 += tx * tx; d1 += ty * ty; d2 += tz * tz; d3 += tw * tw;
            }
            double d = (d0 + d1) + (d2 + d3);
            if (d < best) { best = d; bi = k; }
        }
        sv[tid] = best; sx[tid] = bi;
        __syncthreads();
        for (int s = 128; s > 0; s >>= 1) {
            if (tid < s) {
                if (sv[tid + s] < sv[tid] ||
                    (sv[tid + s] == sv[tid] && sx[tid + s] < sx[tid])) {
                    sv[tid] = sv[tid + s]; sx[tid] = sx[tid + s];
                }
            }
            __syncthreads();
        }
        if (tid == 0) idx[row] = sx[0];
        __syncthreads();
    }
}

// ---------------------------------------------------------------------------
// K4b: hd = relu(emb[idx] @ dec_w1 + dec_b1); gathered rows staged in LDS.
// ---------------------------------------------------------------------------
__global__ __launch_bounds__(512, 4) void k4b_dec1(const int* __restrict__ idx,
                                                   const float* __restrict__ emb,
                                                   const float* __restrict__ w1,
                                                   const float* __restrict__ b1,
                                                   float* __restrict__ hdOut) {
    __shared__ float w1s[LD * HDIM];   // 16 KB
    __shared__ float zqs[64 * 64];     // 16 KB
    int tid = threadIdx.x;
    {
        const float4* src = (const float4*)w1;
        float4* dst = (float4*)w1s;
        dst[tid] = src[tid];
        dst[tid + 512] = src[tid + 512];
    }
    int r0 = blockIdx.x * 64;
    {
        float4* dst = (float4*)zqs;
#pragma unroll
        for (int t = 0; t < 2; ++t) {
            int f = tid + 512 * t;
            int r = f >> 4, q = f & 15;
            int ix = idx[r0 + r];
            dst[f] = *(const float4*)(emb + (size_t)ix * LD + q * 4);
        }
    }
    __syncthreads();

    int lane = tid & 63;
    int w = tid >> 6;
    const float* zb = &zqs[(w * 8) * 64];

    float acc[8];
#pragma unroll
    for (int r = 0; r < 8; ++r) acc[r] = 0.f;

    for (int j0 = 0; j0 < LD; j0 += 8) {
        float wf[8];
#pragma unroll
        for (int jj = 0; jj < 8; ++jj) wf[jj] = w1s[(j0 + jj) * HDIM + lane];
#pragma unroll
        for (int r = 0; r < 8; ++r) {
            const float* zr = zb + r * 64 + j0;
            float4 za = *(const float4*)zr;
            float4 zc = *(const float4*)(zr + 4);
            acc[r] += za.x * wf[0] + za.y * wf[1] + za.z * wf[2] + za.w * wf[3]
                    + zc.x * wf[4] + zc.y * wf[5] + zc.z * wf[6] + zc.w * wf[7];
        }
    }
    float bb = b1[lane];
#pragma unroll
    for (int r = 0; r < 8; ++r) {
        float h = acc[r] + bb;
        hdOut[(size_t)(r0 + w * 8 + r) * HDIM + lane] = fmaxf(h, 0.f);
    }
}

// ---------------------------------------------------------------------------
// K4c: x_recon = hd @ dec_w2 + dec_b2. ct-split, 32KB LDS, 256 thr (proven).
// ---------------------------------------------------------------------------
__global__ __launch_bounds__(256) void k4c_dec2(const float* __restrict__ hd,
                                                const float* __restrict__ w2,
                                                const float* __restrict__ b2,
                                                float* __restrict__ out) {
    __shared__ float w2s[64 * 64];   // 16 KB  [k][c]
    __shared__ float hds[64 * 64];   // 16 KB  [r][k]
    int tid = threadIdx.x;
    int rb  = blockIdx.x >> 2;
    int ct  = blockIdx.x & 3;
    int r0  = rb * 64;

    {
#pragma unroll
        for (int t = 0; t < 4; ++t) {
            int f = tid + 256 * t;
            int j = f >> 4, q = f & 15;
            *(float4*)&w2s[j * 64 + q * 4] =
                *(const float4*)(w2 + (size_t)j * SD + ct * 64 + q * 4);
        }
        const float4* src = (const float4*)(hd + (size_t)r0 * HDIM);
        float4* dst = (float4*)hds;
#pragma unroll
        for (int t = 0; t < 4; ++t) dst[tid + 256 * t] = src[tid + 256 * t];
    }
    __syncthreads();

    int lane = tid & 63;
    int w = tid >> 6;
    const float* hb = &hds[(w * 16) * 64];

    float acc[16];
#pragma unroll
    for (int r = 0; r < 16; ++r) acc[r] = 0.f;

    for (int j0 = 0; j0 < HDIM; j0 += 8) {
        float wf[8];
#pragma unroll
        for (int jj = 0; jj < 8; ++jj) wf[jj] = w2s[(j0 + jj) * 64 + lane];
#pragma unroll
        for (int r = 0; r < 16; ++r) {
            const float* hr = hb + r * 64 + j0;
            float4 ha = *(const float4*)hr;
            float4 hc = *(const float4*)(hr + 4);
            acc[r] += ha.x * wf[0] + ha.y * wf[1] + ha.z * wf[2] + ha.w * wf[3]
                    + hc.x * wf[4] + hc.y * wf[5] + hc.z * wf[6] + hc.w * wf[7];
        }
    }
    float bb = b2[ct * 64 + lane];
#pragma unroll
    for (int r = 0; r < 16; ++r)
        out[(size_t)(r0 + w * 16 + r) * SD + ct * 64 + lane] = acc[r] + bb;
}

// ---------------------------------------------------------------------------
// K4a: z_q = emb[idx]
// ---------------------------------------------------------------------------
__global__ __launch_bounds__(256) void k4a_gather(const int* __restrict__ idx,
                                                  const float* __restrict__ emb,
                                                  float* __restrict__ zq) {
    int g = blockIdx.x * 256 + threadIdx.x;
    int row = g >> 2;
    int q = g & 3;
    int ix = idx[row];
    const float4* src = (const float4*)(emb + (size_t)ix * LD) + q * 4;
    float4* dst = (float4*)(zq + (size_t)row * LD) + q * 4;
    dst[0] = src[0]; dst[1] = src[1]; dst[2] = src[2]; dst[3] = src[3];
}

// ---------------------------------------------------------------------------
extern "C" void kernel_launch(void* const* d_in, const int* in_sizes, int n_in,
                              void* d_out, int out_size, void* d_ws, size_t ws_size,
                              hipStream_t stream) {
    const float* x   = (const float*)d_in[0];
    const float* ew1 = (const float*)d_in[1];
    const float* eb1 = (const float*)d_in[2];
    const float* ew2 = (const float*)d_in[3];
    const float* eb2 = (const float*)d_in[4];
    const float* emb = (const float*)d_in[5];
    const float* dw1 = (const float*)d_in[6];
    const float* db1 = (const float*)d_in[7];
    const float* dw2 = (const float*)d_in[8];
    const float* db2 = (const float*)d_in[9];

    float* out  = (float*)d_out;
    float* xrec = out;                               // [B,256] (written LAST)
    float* zE   = out + (size_t)BATCH * SD;          // [B,64]
    float* zQ   = zE + (size_t)BATCH * LD;           // [B,64]; h/hd scratch

    // transient scratch inside the x_recon region (free until k4c):
    char* xb = (char*)xrec;
    unsigned short* zh  = (unsigned short*)xb;                        // 4 MB
    unsigned short* zl  = (unsigned short*)(xb + (4u << 20));         // 4 MB
    unsigned short* eh  = (unsigned short*)(xb + (8u << 20));         // 256 KB
    unsigned short* el  = (unsigned short*)(xb + (8u << 20) + (NEMB * LD * 2)); // 256 KB
    float*          e2q = (float*)(xb + (9u << 20));                  // 8 KB

    char* ws = (char*)d_ws;
    int*  count = (int*)ws;                                   // 4 B
    int*  idxA  = (int*)(ws + 16384);                         // 128 KB
    int*  list  = (int*)(ws + 16384 + (size_t)BATCH * 4);     // 128 KB

    hipLaunchKernelGGL(k0_prep,   dim3(NEMB / 256),  dim3(256), 0, stream, emb, e2q, eh, el, count);
    hipLaunchKernelGGL(k1a_enc1,  dim3(BATCH / 64),  dim3(512), 0, stream, x, ew1, eb1, zQ);
    hipLaunchKernelGGL(k1b_enc2,  dim3(BATCH / 64),  dim3(512), 0, stream, zQ, ew2, eb2, zE, zh, zl);
    hipLaunchKernelGGL(k2_mfma,   dim3(BATCH / 32),  dim3(256), 0, stream, zh, zl, eh, el, e2q, idxA, list, count);
    hipLaunchKernelGGL(k3_refine, dim3(128),         dim3(256), 0, stream, zE, emb, count, list, idxA);
    hipLaunchKernelGGL(k4b_dec1,  dim3(BATCH / 64),  dim3(512), 0, stream, idxA, emb, dw1, db1, zQ);
    hipLaunchKernelGGL(k4c_dec2,  dim3(BATCH / 64 * 4), dim3(256), 0, stream, zQ, dw2, db2, xrec);
    hipLaunchKernelGGL(k4a_gather, dim3(BATCH * 4 / 256), dim3(256), 0, stream, idxA, emb, zQ);
}

// Round 7
// 173.387 us; speedup vs baseline: 1.0411x; 1.0411x over previous
//
#include <hip/hip_runtime.h>

#define BATCH   32768
#define SD      256
#define LD      64
#define HDIM    64
#define NEMB    2048
#define REFINE_THR_Q 5e-4f   // gap in q-units; s-gap = 2*q-gap -> 1e-3 effective

typedef short  short8 __attribute__((ext_vector_type(8)));
typedef float  f32x4  __attribute__((ext_vector_type(4)));

// bf16 RNE helpers (bit ops, finite data)
__device__ __forceinline__ unsigned short f2bf(float f) {
    unsigned int u = __float_as_uint(f);
    u = (u + 0x7FFFu + ((u >> 16) & 1u)) >> 16;
    return (unsigned short)u;
}
__device__ __forceinline__ float bf2f(unsigned short h) {
    return __uint_as_float(((unsigned int)h) << 16);
}

// ---------------------------------------------------------------------------
// K0: e2q[k] = -0.5*||emb[k]||^2 (MFMA C-init), bf16 split eh/el, zero counter.
// ---------------------------------------------------------------------------
__global__ __launch_bounds__(256) void k0_prep(const float* __restrict__ emb,
                                               float* __restrict__ e2q,
                                               unsigned short* __restrict__ eh,
                                               unsigned short* __restrict__ el,
                                               int* __restrict__ count) {
    int k = blockIdx.x * 256 + threadIdx.x;
    if (k == 0) *count = 0;
    const float* er = emb + (size_t)k * LD;
    unsigned short hrow[LD], lrow[LD];
    float s = 0.f;
#pragma unroll
    for (int q = 0; q < LD; ++q) {
        float v = er[q];
        s += v * v;
        unsigned short h = f2bf(v);
        hrow[q] = h;
        lrow[q] = f2bf(v - bf2f(h));
    }
    e2q[k] = -0.5f * s;
    short8* dh = (short8*)(eh + (size_t)k * LD);
    short8* dl = (short8*)(el + (size_t)k * LD);
#pragma unroll
    for (int q = 0; q < 8; ++q) {
        dh[q] = *(short8*)&hrow[q * 8];
        dl[q] = *(short8*)&lrow[q * 8];
    }
}

// ---------------------------------------------------------------------------
// K1a: h = relu(x @ enc_w1 + enc_b1)  (proven fast round 4/5)
// ---------------------------------------------------------------------------
__global__ __launch_bounds__(512, 4) void k1a_enc1(const float* __restrict__ x,
                                                   const float* __restrict__ w1,
                                                   const float* __restrict__ b1,
                                                   float* __restrict__ hOut) {
    __shared__ float w1s[SD * HDIM];       // 64 KB
    __shared__ float xs[2][64 * 32];       // 16 KB
    int tid = threadIdx.x;
    {
        const float4* src = (const float4*)w1;
        float4* dst = (float4*)w1s;
#pragma unroll
        for (int t = 0; t < 8; ++t) dst[tid + 512 * t] = src[tid + 512 * t];
    }
    int r0 = blockIdx.x * 64;
    int sr = tid >> 3;
    int sq = tid & 7;
    const float* xrow = x + (size_t)(r0 + sr) * SD + sq * 4;

    {
        float4 v = *(const float4*)xrow;
        *(float4*)&xs[0][sr * 32 + sq * 4] = v;
    }
    __syncthreads();

    int lane = tid & 63;
    int w = tid >> 6;
    float acc[8];
#pragma unroll
    for (int r = 0; r < 8; ++r) acc[r] = 0.f;

    for (int c = 0; c < 8; ++c) {
        float4 nv;
        if (c < 7) nv = *(const float4*)(xrow + (c + 1) * 32);
        const float* xb = &xs[c & 1][(w * 8) * 32];
        int kb = c * 32;
#pragma unroll
        for (int i0 = 0; i0 < 32; i0 += 8) {
            float wf[8];
#pragma unroll
            for (int jj = 0; jj < 8; ++jj) wf[jj] = w1s[(kb + i0 + jj) * HDIM + lane];
#pragma unroll
            for (int r = 0; r < 8; ++r) {
                const float* xr = xb + r * 32 + i0;
                float4 xa = *(const float4*)xr;
                float4 xc = *(const float4*)(xr + 4);
                acc[r] += xa.x * wf[0] + xa.y * wf[1] + xa.z * wf[2] + xa.w * wf[3]
                        + xc.x * wf[4] + xc.y * wf[5] + xc.z * wf[6] + xc.w * wf[7];
            }
        }
        __syncthreads();
        if (c < 7) *(float4*)&xs[(c + 1) & 1][sr * 32 + sq * 4] = nv;
        __syncthreads();
    }
    float bb = b1[lane];
#pragma unroll
    for (int r = 0; r < 8; ++r) {
        float h = acc[r] + bb;
        hOut[(size_t)(r0 + w * 8 + r) * HDIM + lane] = fmaxf(h, 0.f);
    }
}

// ---------------------------------------------------------------------------
// K1b: z_e = h @ enc_w2 + enc_b2, fused bf16 split z -> zh, zl
// ---------------------------------------------------------------------------
__global__ __launch_bounds__(512, 4) void k1b_enc2(const float* __restrict__ hIn,
                                                   const float* __restrict__ w2,
                                                   const float* __restrict__ b2,
                                                   float* __restrict__ zOut,
                                                   unsigned short* __restrict__ zh,
                                                   unsigned short* __restrict__ zl) {
    __shared__ float w2s[HDIM * LD];   // 16 KB
    __shared__ float hs[64 * 64];      // 16 KB
    int tid = threadIdx.x;
    {
        const float4* src = (const float4*)w2;
        float4* dst = (float4*)w2s;
        dst[tid] = src[tid];
        dst[tid + 512] = src[tid + 512];
    }
    int r0 = blockIdx.x * 64;
    {
        const float4* src = (const float4*)(hIn + (size_t)r0 * HDIM);
        float4* dst = (float4*)hs;
        dst[tid] = src[tid];
        dst[tid + 512] = src[tid + 512];
    }
    __syncthreads();

    int lane = tid & 63;
    int w = tid >> 6;
    const float* hb = &hs[(w * 8) * 64];

    float acc[8];
#pragma unroll
    for (int r = 0; r < 8; ++r) acc[r] = 0.f;

    for (int j0 = 0; j0 < HDIM; j0 += 8) {
        float wf[8];
#pragma unroll
        for (int jj = 0; jj < 8; ++jj) wf[jj] = w2s[(j0 + jj) * LD + lane];
#pragma unroll
        for (int r = 0; r < 8; ++r) {
            const float* hr = hb + r * 64 + j0;
            float4 ha = *(const float4*)hr;
            float4 hc = *(const float4*)(hr + 4);
            acc[r] += ha.x * wf[0] + ha.y * wf[1] + ha.z * wf[2] + ha.w * wf[3]
                    + hc.x * wf[4] + hc.y * wf[5] + hc.z * wf[6] + hc.w * wf[7];
        }
    }
    float bb = b2[lane];
#pragma unroll
    for (int r = 0; r < 8; ++r) {
        float z = acc[r] + bb;
        size_t o = (size_t)(r0 + w * 8 + r) * LD + lane;
        zOut[o] = z;
        unsigned short h = f2bf(z);
        zh[o] = h;
        zl[o] = f2bf(z - bf2f(h));
    }
}

// ---------------------------------------------------------------------------
// K2: MFMA split-bf16 screen, max-form.  q = z.e - 0.5||e||^2 (C-init = e2q).
// 512 blocks x 512 thr (8 waves): 64 rows/block, wave = NEMB/8 = 256 codes.
// Per wave: 4 B-groups -> 4 independent 6-MFMA chains + 4 epilogue groups
// per tile (round-5 ILP) at 16 waves/CU (2 blocks x 8 waves).
// C layout (m89): col = lane&15 = batch row, row = (lane>>4)*4+reg = code.
// ---------------------------------------------------------------------------
__global__ __launch_bounds__(512, 4) void k2_mfma(const unsigned short* __restrict__ zh,
                                                  const unsigned short* __restrict__ zl,
                                                  const unsigned short* __restrict__ eh,
                                                  const unsigned short* __restrict__ el,
                                                  const float* __restrict__ e2q,
                                                  int* __restrict__ idx,
                                                  int* __restrict__ list,
                                                  int* __restrict__ count) {
    int tid  = threadIdx.x;
    int lane = tid & 63;
    int w    = tid >> 6;           // wave -> code eighth (0..7)
    int rb   = blockIdx.x * 64;    // 64 batch rows per block
    int lo   = lane & 15;
    int hi   = lane >> 4;

    short8 bh[4][2], bl[4][2];
#pragma unroll
    for (int g = 0; g < 4; ++g) {
        size_t zo = (size_t)(rb + g * 16 + lo) * LD + hi * 8;
        bh[g][0] = *(const short8*)(zh + zo);
        bh[g][1] = *(const short8*)(zh + zo + 32);
        bl[g][0] = *(const short8*)(zl + zo);
        bl[g][1] = *(const short8*)(zl + zo + 32);
    }

    float bb[4], ss[4];
    int   ii[4];
#pragma unroll
    for (int g = 0; g < 4; ++g) { bb[g] = -3.0e38f; ss[g] = -3.0e38f; ii[g] = 0; }

    const int cbase = w * (NEMB / 8);
    const unsigned short* ehp = eh + (size_t)(cbase + lo) * LD + hi * 8;
    const unsigned short* elp = el + (size_t)(cbase + lo) * LD + hi * 8;

    short8 a0 = *(const short8*)(ehp);
    short8 a1 = *(const short8*)(ehp + 32);
    short8 a2 = *(const short8*)(elp);
    short8 a3 = *(const short8*)(elp + 32);
    f32x4 e2c = *(const f32x4*)(e2q + cbase + hi * 4);

    for (int t = 0; t < NEMB / 8 / 16; ++t) {
        short8 n0 = a0, n1 = a1, n2 = a2, n3 = a3;
        f32x4 e2n = e2c;
        if (t < NEMB / 8 / 16 - 1) {
            const unsigned short* ph = ehp + (size_t)(t + 1) * 16 * LD;
            const unsigned short* pl = elp + (size_t)(t + 1) * 16 * LD;
            n0 = *(const short8*)(ph);
            n1 = *(const short8*)(ph + 32);
            n2 = *(const short8*)(pl);
            n3 = *(const short8*)(pl + 32);
            e2n = *(const f32x4*)(e2q + cbase + (t + 1) * 16 + hi * 4);
        }

        f32x4 acc[4];
#pragma unroll
        for (int g = 0; g < 4; ++g) {
            f32x4 c;
            c = __builtin_amdgcn_mfma_f32_16x16x32_bf16(a0, bh[g][0], e2c, 0, 0, 0);
            c = __builtin_amdgcn_mfma_f32_16x16x32_bf16(a1, bh[g][1], c, 0, 0, 0);
            c = __builtin_amdgcn_mfma_f32_16x16x32_bf16(a2, bh[g][0], c, 0, 0, 0);
            c = __builtin_amdgcn_mfma_f32_16x16x32_bf16(a3, bh[g][1], c, 0, 0, 0);
            c = __builtin_amdgcn_mfma_f32_16x16x32_bf16(a0, bl[g][0], c, 0, 0, 0);
            c = __builtin_amdgcn_mfma_f32_16x16x32_bf16(a1, bl[g][1], c, 0, 0, 0);
            acc[g] = c;
        }

        int base4 = cbase + t * 16 + hi * 4;
#pragma unroll
        for (int g = 0; g < 4; ++g) {
            float s0 = acc[g][0], s1 = acc[g][1], s2 = acc[g][2], s3 = acc[g][3];
            float M01 = fmaxf(s0, s1), L01 = fminf(s0, s1);
            float M23 = fmaxf(s2, s3), L23 = fminf(s2, s3);
            int   d01 = (s1 > s0) ? 1 : 0;
            int   d23 = (s3 > s2) ? 3 : 2;
            bool  cp  = (M23 > M01);
            float m   = fmaxf(M01, M23);
            float mn  = fminf(M01, M23);
            int   d   = cp ? d23 : d01;
            float hw  = cp ? L23 : L01;
            float t2  = fmaxf(mn, hw);
            ii[g] = (m > bb[g]) ? (base4 + d) : ii[g];
            ss[g] = fmaxf(fmaxf(fminf(bb[g], m), t2), ss[g]);
            bb[g] = fmaxf(bb[g], m);
        }

        a0 = n0; a1 = n1; a2 = n2; a3 = n3; e2c = e2n;
    }

    // cross-lane merge over hi (lanes c, c+16, c+32, c+48)
#pragma unroll
    for (int off = 16; off <= 32; off <<= 1) {
#pragma unroll
        for (int g = 0; g < 4; ++g) {
            float ob = __shfl_xor(bb[g], off);
            float os = __shfl_xor(ss[g], off);
            int   oi = __shfl_xor(ii[g], off);
            ss[g] = fmaxf(fmaxf(fminf(bb[g], ob), os), ss[g]);
            ii[g] = (ob > bb[g]) ? oi : ii[g];
            bb[g] = fmaxf(bb[g], ob);
        }
    }

    // cross-wave merge (8 code eighths) via LDS
    __shared__ float Lb[8][64];
    __shared__ float Ls[8][64];
    __shared__ int   Li[8][64];
    if (lane < 16) {
#pragma unroll
        for (int g = 0; g < 4; ++g) {
            Lb[w][g * 16 + lane] = bb[g];
            Ls[w][g * 16 + lane] = ss[g];
            Li[w][g * 16 + lane] = ii[g];
        }
    }
    __syncthreads();

    if (tid < 64) {
        float B = Lb[0][tid], S = Ls[0][tid];
        int   I = Li[0][tid];
#pragma unroll
        for (int w2 = 1; w2 < 8; ++w2) {
            float ob = Lb[w2][tid], os = Ls[w2][tid];
            int   oi = Li[w2][tid];
            S = fmaxf(fmaxf(fminf(B, ob), os), S);
            I = (ob > B) ? oi : I;
            B = fmaxf(B, ob);
        }
        idx[rb + tid] = I;
        if (B - S < REFINE_THR_Q) {
            int p = atomicAdd(count, 1);
            list[p] = rb + tid;
        }
    }
}

// ---------------------------------------------------------------------------
// K3: exact f64 rescan of flagged near-tie rows.
// ---------------------------------------------------------------------------
__global__ __launch_bounds__(256) void k3_refine(const float* __restrict__ z,
                                                 const float* __restrict__ emb,
                                                 const int* __restrict__ count,
                                                 const int* __restrict__ list,
                                                 int* __restrict__ idx) {
    __shared__ double sv[256];
    __shared__ int    sx[256];
    int tid = threadIdx.x;
    int n = *count;
    for (int g = blockIdx.x; g < n; g += gridDim.x) {
        int row = list[g];
        const float4* zr4 = (const float4*)(z + (size_t)row * LD);
        float4 zv[16];
#pragma unroll
        for (int q = 0; q < 16; ++q) zv[q] = zr4[q];

        double best = 1.0e300;
        int bi = NEMB;
#pragma unroll 2
        for (int c = 0; c < 8; ++c) {
            int k = tid * 8 + c;
            const float4* er = (const float4*)(emb + (size_t)k * LD);
            double d0 = 0.0, d1 = 0.0, d2 = 0.0, d3 = 0.0;
#pragma unroll
            for (int q = 0; q < 16; ++q) {
                float4 e4 = er[q];
                double tx = (double)zv[q].x - (double)e4.x;
                double ty = (double)zv[q].y - (double)e4.y;
                double tz = (double)zv[q].z - (double)e4.z;
                double tw = (double)zv[q].w - (double)e4.w;
                d0 += tx * tx; d1 += ty * ty; d2 += tz * tz; d3 += tw * tw;
            }
            double d = (d0 + d1) + (d2 + d3);
            if (d < best) { best = d; bi = k; }
        }
        sv[tid] = best; sx[tid] = bi;
        __syncthreads();
        for (int s = 128; s > 0; s >>= 1) {
            if (tid < s) {
                if (sv[tid + s] < sv[tid] ||
                    (sv[tid + s] == sv[tid] && sx[tid + s] < sx[tid])) {
                    sv[tid] = sv[tid + s]; sx[tid] = sx[tid + s];
                }
            }
            __syncthreads();
        }
        if (tid == 0) idx[row] = sx[0];
        __syncthreads();
    }
}

// ---------------------------------------------------------------------------
// K4b: hd = relu(emb[idx] @ dec_w1 + dec_b1); gathered rows staged in LDS.
// ---------------------------------------------------------------------------
__global__ __launch_bounds__(512, 4) void k4b_dec1(const int* __restrict__ idx,
                                                   const float* __restrict__ emb,
                                                   const float* __restrict__ w1,
                                                   const float* __restrict__ b1,
                                                   float* __restrict__ hdOut) {
    __shared__ float w1s[LD * HDIM];   // 16 KB
    __shared__ float zqs[64 * 64];     // 16 KB
    int tid = threadIdx.x;
    {
        const float4* src = (const float4*)w1;
        float4* dst = (float4*)w1s;
        dst[tid] = src[tid];
        dst[tid + 512] = src[tid + 512];
    }
    int r0 = blockIdx.x * 64;
    {
        float4* dst = (float4*)zqs;
#pragma unroll
        for (int t = 0; t < 2; ++t) {
            int f = tid + 512 * t;
            int r = f >> 4, q = f & 15;
            int ix = idx[r0 + r];
            dst[f] = *(const float4*)(emb + (size_t)ix * LD + q * 4);
        }
    }
    __syncthreads();

    int lane = tid & 63;
    int w = tid >> 6;
    const float* zb = &zqs[(w * 8) * 64];

    float acc[8];
#pragma unroll
    for (int r = 0; r < 8; ++r) acc[r] = 0.f;

    for (int j0 = 0; j0 < LD; j0 += 8) {
        float wf[8];
#pragma unroll
        for (int jj = 0; jj < 8; ++jj) wf[jj] = w1s[(j0 + jj) * HDIM + lane];
#pragma unroll
        for (int r = 0; r < 8; ++r) {
            const float* zr = zb + r * 64 + j0;
            float4 za = *(const float4*)zr;
            float4 zc = *(const float4*)(zr + 4);
            acc[r] += za.x * wf[0] + za.y * wf[1] + za.z * wf[2] + za.w * wf[3]
                    + zc.x * wf[4] + zc.y * wf[5] + zc.z * wf[6] + zc.w * wf[7];
        }
    }
    float bb = b1[lane];
#pragma unroll
    for (int r = 0; r < 8; ++r) {
        float h = acc[r] + bb;
        hdOut[(size_t)(r0 + w * 8 + r) * HDIM + lane] = fmaxf(h, 0.f);
    }
}

// ---------------------------------------------------------------------------
// K4c: x_recon = hd @ dec_w2 + dec_b2. ct-split, 32KB LDS, 256 thr (proven).
// ---------------------------------------------------------------------------
__global__ __launch_bounds__(256) void k4c_dec2(const float* __restrict__ hd,
                                                const float* __restrict__ w2,
                                                const float* __restrict__ b2,
                                                float* __restrict__ out) {
    __shared__ float w2s[64 * 64];   // 16 KB  [k][c]
    __shared__ float hds[64 * 64];   // 16 KB  [r][k]
    int tid = threadIdx.x;
    int rb  = blockIdx.x >> 2;
    int ct  = blockIdx.x & 3;
    int r0  = rb * 64;

    {
#pragma unroll
        for (int t = 0; t < 4; ++t) {
            int f = tid + 256 * t;
            int j = f >> 4, q = f & 15;
            *(float4*)&w2s[j * 64 + q * 4] =
                *(const float4*)(w2 + (size_t)j * SD + ct * 64 + q * 4);
        }
        const float4* src = (const float4*)(hd + (size_t)r0 * HDIM);
        float4* dst = (float4*)hds;
#pragma unroll
        for (int t = 0; t < 4; ++t) dst[tid + 256 * t] = src[tid + 256 * t];
    }
    __syncthreads();

    int lane = tid & 63;
    int w = tid >> 6;
    const float* hb = &hds[(w * 16) * 64];

    float acc[16];
#pragma unroll
    for (int r = 0; r < 16; ++r) acc[r] = 0.f;

    for (int j0 = 0; j0 < HDIM; j0 += 8) {
        float wf[8];
#pragma unroll
        for (int jj = 0; jj < 8; ++jj) wf[jj] = w2s[(j0 + jj) * 64 + lane];
#pragma unroll
        for (int r = 0; r < 16; ++r) {
            const float* hr = hb + r * 64 + j0;
            float4 ha = *(const float4*)hr;
            float4 hc = *(const float4*)(hr + 4);
            acc[r] += ha.x * wf[0] + ha.y * wf[1] + ha.z * wf[2] + ha.w * wf[3]
                    + hc.x * wf[4] + hc.y * wf[5] + hc.z * wf[6] + hc.w * wf[7];
        }
    }
    float bb = b2[ct * 64 + lane];
#pragma unroll
    for (int r = 0; r < 16; ++r)
        out[(size_t)(r0 + w * 16 + r) * SD + ct * 64 + lane] = acc[r] + bb;
}

// ---------------------------------------------------------------------------
// K4a: z_q = emb[idx]
// ---------------------------------------------------------------------------
__global__ __launch_bounds__(256) void k4a_gather(const int* __restrict__ idx,
                                                  const float* __restrict__ emb,
                                                  float* __restrict__ zq) {
    int g = blockIdx.x * 256 + threadIdx.x;
    int row = g >> 2;
    int q = g & 3;
    int ix = idx[row];
    const float4* src = (const float4*)(emb + (size_t)ix * LD) + q * 4;
    float4* dst = (float4*)(zq + (size_t)row * LD) + q * 4;
    dst[0] = src[0]; dst[1] = src[1]; dst[2] = src[2]; dst[3] = src[3];
}

// ---------------------------------------------------------------------------
extern "C" void kernel_launch(void* const* d_in, const int* in_sizes, int n_in,
                              void* d_out, int out_size, void* d_ws, size_t ws_size,
                              hipStream_t stream) {
    const float* x   = (const float*)d_in[0];
    const float* ew1 = (const float*)d_in[1];
    const float* eb1 = (const float*)d_in[2];
    const float* ew2 = (const float*)d_in[3];
    const float* eb2 = (const float*)d_in[4];
    const float* emb = (const float*)d_in[5];
    const float* dw1 = (const float*)d_in[6];
    const float* db1 = (const float*)d_in[7];
    const float* dw2 = (const float*)d_in[8];
    const float* db2 = (const float*)d_in[9];

    float* out  = (float*)d_out;
    float* xrec = out;                               // [B,256] (written LAST)
    float* zE   = out + (size_t)BATCH * SD;          // [B,64]
    float* zQ   = zE + (size_t)BATCH * LD;           // [B,64]; h/hd scratch

    // transient scratch inside the x_recon region (free until k4c):
    char* xb = (char*)xrec;
    unsigned short* zh  = (unsigned short*)xb;                        // 4 MB
    unsigned short* zl  = (unsigned short*)(xb + (4u << 20));         // 4 MB
    unsigned short* eh  = (unsigned short*)(xb + (8u << 20));         // 256 KB
    unsigned short* el  = (unsigned short*)(xb + (8u << 20) + (NEMB * LD * 2)); // 256 KB
    float*          e2q = (float*)(xb + (9u << 20));                  // 8 KB

    char* ws = (char*)d_ws;
    int*  count = (int*)ws;                                   // 4 B
    int*  idxA  = (int*)(ws + 16384);                         // 128 KB
    int*  list  = (int*)(ws + 16384 + (size_t)BATCH * 4);     // 128 KB

    hipLaunchKernelGGL(k0_prep,   dim3(NEMB / 256),  dim3(256), 0, stream, emb, e2q, eh, el, count);
    hipLaunchKernelGGL(k1a_enc1,  dim3(BATCH / 64),  dim3(512), 0, stream, x, ew1, eb1, zQ);
    hipLaunchKernelGGL(k1b_enc2,  dim3(BATCH / 64),  dim3(512), 0, stream, zQ, ew2, eb2, zE, zh, zl);
    hipLaunchKernelGGL(k2_mfma,   dim3(BATCH / 64),  dim3(512), 0, stream, zh, zl, eh, el, e2q, idxA, list, count);
    hipLaunchKernelGGL(k3_refine, dim3(128),         dim3(256), 0, stream, zE, emb, count, list, idxA);
    hipLaunchKernelGGL(k4b_dec1,  dim3(BATCH / 64),  dim3(512), 0, stream, idxA, emb, dw1, db1, zQ);
    hipLaunchKernelGGL(k4c_dec2,  dim3(BATCH / 64 * 4), dim3(256), 0, stream, zQ, dw2, db2, xrec);
    hipLaunchKernelGGL(k4a_gather, dim3(BATCH * 4 / 256), dim3(256), 0, stream, idxA, emb, zQ);
}

// Round 8
// 151.983 us; speedup vs baseline: 1.1877x; 1.1408x over previous
//
#include <hip/hip_runtime.h>

#define BATCH   32768
#define SD      256
#define LD      64
#define HDIM    64
#define NEMB    2048
#define REFINE_THR_Q 5e-4f   // gap in q-units; s-gap = 2*q-gap -> 1e-3 effective

typedef short  short8 __attribute__((ext_vector_type(8)));
typedef float  f32x4  __attribute__((ext_vector_type(4)));

// bf16 RNE helpers (bit ops, finite data)
__device__ __forceinline__ unsigned short f2bf(float f) {
    unsigned int u = __float_as_uint(f);
    u = (u + 0x7FFFu + ((u >> 16) & 1u)) >> 16;
    return (unsigned short)u;
}
__device__ __forceinline__ float bf2f(unsigned short h) {
    return __uint_as_float(((unsigned int)h) << 16);
}

// ---------------------------------------------------------------------------
// K0: e2q[k] = -0.5*||emb[k]||^2 (MFMA C-init), bf16 split eh/el, zero counter.
// ---------------------------------------------------------------------------
__global__ __launch_bounds__(256) void k0_prep(const float* __restrict__ emb,
                                               float* __restrict__ e2q,
                                               unsigned short* __restrict__ eh,
                                               unsigned short* __restrict__ el,
                                               int* __restrict__ count) {
    int k = blockIdx.x * 256 + threadIdx.x;
    if (k == 0) *count = 0;
    const float* er = emb + (size_t)k * LD;
    unsigned short hrow[LD], lrow[LD];
    float s = 0.f;
#pragma unroll
    for (int q = 0; q < LD; ++q) {
        float v = er[q];
        s += v * v;
        unsigned short h = f2bf(v);
        hrow[q] = h;
        lrow[q] = f2bf(v - bf2f(h));
    }
    e2q[k] = -0.5f * s;
    short8* dh = (short8*)(eh + (size_t)k * LD);
    short8* dl = (short8*)(el + (size_t)k * LD);
#pragma unroll
    for (int q = 0; q < 8; ++q) {
        dh[q] = *(short8*)&hrow[q * 8];
        dl[q] = *(short8*)&lrow[q * 8];
    }
}

// ---------------------------------------------------------------------------
// K1a: h = relu(x @ enc_w1 + enc_b1)  (proven fast round 4/5)
// ---------------------------------------------------------------------------
__global__ __launch_bounds__(512, 4) void k1a_enc1(const float* __restrict__ x,
                                                   const float* __restrict__ w1,
                                                   const float* __restrict__ b1,
                                                   float* __restrict__ hOut) {
    __shared__ float w1s[SD * HDIM];       // 64 KB
    __shared__ float xs[2][64 * 32];       // 16 KB
    int tid = threadIdx.x;
    {
        const float4* src = (const float4*)w1;
        float4* dst = (float4*)w1s;
#pragma unroll
        for (int t = 0; t < 8; ++t) dst[tid + 512 * t] = src[tid + 512 * t];
    }
    int r0 = blockIdx.x * 64;
    int sr = tid >> 3;
    int sq = tid & 7;
    const float* xrow = x + (size_t)(r0 + sr) * SD + sq * 4;

    {
        float4 v = *(const float4*)xrow;
        *(float4*)&xs[0][sr * 32 + sq * 4] = v;
    }
    __syncthreads();

    int lane = tid & 63;
    int w = tid >> 6;
    float acc[8];
#pragma unroll
    for (int r = 0; r < 8; ++r) acc[r] = 0.f;

    for (int c = 0; c < 8; ++c) {
        float4 nv;
        if (c < 7) nv = *(const float4*)(xrow + (c + 1) * 32);
        const float* xb = &xs[c & 1][(w * 8) * 32];
        int kb = c * 32;
#pragma unroll
        for (int i0 = 0; i0 < 32; i0 += 8) {
            float wf[8];
#pragma unroll
            for (int jj = 0; jj < 8; ++jj) wf[jj] = w1s[(kb + i0 + jj) * HDIM + lane];
#pragma unroll
            for (int r = 0; r < 8; ++r) {
                const float* xr = xb + r * 32 + i0;
                float4 xa = *(const float4*)xr;
                float4 xc = *(const float4*)(xr + 4);
                acc[r] += xa.x * wf[0] + xa.y * wf[1] + xa.z * wf[2] + xa.w * wf[3]
                        + xc.x * wf[4] + xc.y * wf[5] + xc.z * wf[6] + xc.w * wf[7];
            }
        }
        __syncthreads();
        if (c < 7) *(float4*)&xs[(c + 1) & 1][sr * 32 + sq * 4] = nv;
        __syncthreads();
    }
    float bb = b1[lane];
#pragma unroll
    for (int r = 0; r < 8; ++r) {
        float h = acc[r] + bb;
        hOut[(size_t)(r0 + w * 8 + r) * HDIM + lane] = fmaxf(h, 0.f);
    }
}

// ---------------------------------------------------------------------------
// K1b: z_e = h @ enc_w2 + enc_b2, fused bf16 split z -> zh, zl
// ---------------------------------------------------------------------------
__global__ __launch_bounds__(512, 4) void k1b_enc2(const float* __restrict__ hIn,
                                                   const float* __restrict__ w2,
                                                   const float* __restrict__ b2,
                                                   float* __restrict__ zOut,
                                                   unsigned short* __restrict__ zh,
                                                   unsigned short* __restrict__ zl) {
    __shared__ float w2s[HDIM * LD];   // 16 KB
    __shared__ float hs[64 * 64];      // 16 KB
    int tid = threadIdx.x;
    {
        const float4* src = (const float4*)w2;
        float4* dst = (float4*)w2s;
        dst[tid] = src[tid];
        dst[tid + 512] = src[tid + 512];
    }
    int r0 = blockIdx.x * 64;
    {
        const float4* src = (const float4*)(hIn + (size_t)r0 * HDIM);
        float4* dst = (float4*)hs;
        dst[tid] = src[tid];
        dst[tid + 512] = src[tid + 512];
    }
    __syncthreads();

    int lane = tid & 63;
    int w = tid >> 6;
    const float* hb = &hs[(w * 8) * 64];

    float acc[8];
#pragma unroll
    for (int r = 0; r < 8; ++r) acc[r] = 0.f;

    for (int j0 = 0; j0 < HDIM; j0 += 8) {
        float wf[8];
#pragma unroll
        for (int jj = 0; jj < 8; ++jj) wf[jj] = w2s[(j0 + jj) * LD + lane];
#pragma unroll
        for (int r = 0; r < 8; ++r) {
            const float* hr = hb + r * 64 + j0;
            float4 ha = *(const float4*)hr;
            float4 hc = *(const float4*)(hr + 4);
            acc[r] += ha.x * wf[0] + ha.y * wf[1] + ha.z * wf[2] + ha.w * wf[3]
                    + hc.x * wf[4] + hc.y * wf[5] + hc.z * wf[6] + hc.w * wf[7];
        }
    }
    float bb = b2[lane];
#pragma unroll
    for (int r = 0; r < 8; ++r) {
        float z = acc[r] + bb;
        size_t o = (size_t)(r0 + w * 8 + r) * LD + lane;
        zOut[o] = z;
        unsigned short h = f2bf(z);
        zh[o] = h;
        zl[o] = f2bf(z - bf2f(h));
    }
}

// ---------------------------------------------------------------------------
// K2: MFMA split-bf16 screen, max-form, SLIM in-loop tracker.
// R5 geometry: 512 blocks x 256 thr (4 waves), 64 rows/block, wave = quarter
// codebook (512 codes, 32 tiles), 4 row-groups -> 4 independent MFMA chains.
// In-loop per group: m=max4(acc); on m>bb save quad qv + tile tt; track
// bb (best) and bb2 (second over quad-maxima). Index + within-quad second
// extracted ONCE post-loop; merges unchanged. Ties -> gap 0 -> k3 exact.
// C layout (m89): col = lane&15 = batch row, row = (lane>>4)*4+reg = code.
// ---------------------------------------------------------------------------
__global__ __launch_bounds__(256, 2) void k2_mfma(const unsigned short* __restrict__ zh,
                                                  const unsigned short* __restrict__ zl,
                                                  const unsigned short* __restrict__ eh,
                                                  const unsigned short* __restrict__ el,
                                                  const float* __restrict__ e2q,
                                                  int* __restrict__ idx,
                                                  int* __restrict__ list,
                                                  int* __restrict__ count) {
    int tid  = threadIdx.x;
    int lane = tid & 63;
    int w    = tid >> 6;           // wave -> code quarter
    int rb   = blockIdx.x * 64;    // 64 batch rows per block
    int lo   = lane & 15;
    int hi   = lane >> 4;

    short8 bh[4][2], bl[4][2];
#pragma unroll
    for (int g = 0; g < 4; ++g) {
        size_t zo = (size_t)(rb + g * 16 + lo) * LD + hi * 8;
        bh[g][0] = *(const short8*)(zh + zo);
        bh[g][1] = *(const short8*)(zh + zo + 32);
        bl[g][0] = *(const short8*)(zl + zo);
        bl[g][1] = *(const short8*)(zl + zo + 32);
    }

    float bb[4], b2v[4];
    f32x4 qv[4];
    int   tt[4];
#pragma unroll
    for (int g = 0; g < 4; ++g) {
        bb[g] = -3.0e38f; b2v[g] = -3.0e38f; tt[g] = 0;
        qv[g][0] = qv[g][1] = qv[g][2] = qv[g][3] = -3.0e38f;
    }

    const int cbase = w * (NEMB / 4);
    const unsigned short* ehp = eh + (size_t)(cbase + lo) * LD + hi * 8;
    const unsigned short* elp = el + (size_t)(cbase + lo) * LD + hi * 8;

    short8 a0 = *(const short8*)(ehp);
    short8 a1 = *(const short8*)(ehp + 32);
    short8 a2 = *(const short8*)(elp);
    short8 a3 = *(const short8*)(elp + 32);
    f32x4 e2c = *(const f32x4*)(e2q + cbase + hi * 4);

    for (int t = 0; t < NEMB / 4 / 16; ++t) {
        short8 n0 = a0, n1 = a1, n2 = a2, n3 = a3;
        f32x4 e2n = e2c;
        if (t < NEMB / 4 / 16 - 1) {
            const unsigned short* ph = ehp + (size_t)(t + 1) * 16 * LD;
            const unsigned short* pl = elp + (size_t)(t + 1) * 16 * LD;
            n0 = *(const short8*)(ph);
            n1 = *(const short8*)(ph + 32);
            n2 = *(const short8*)(pl);
            n3 = *(const short8*)(pl + 32);
            e2n = *(const f32x4*)(e2q + cbase + (t + 1) * 16 + hi * 4);
        }

        f32x4 acc[4];
#pragma unroll
        for (int g = 0; g < 4; ++g) {
            f32x4 c;
            c = __builtin_amdgcn_mfma_f32_16x16x32_bf16(a0, bh[g][0], e2c, 0, 0, 0);
            c = __builtin_amdgcn_mfma_f32_16x16x32_bf16(a1, bh[g][1], c, 0, 0, 0);
            c = __builtin_amdgcn_mfma_f32_16x16x32_bf16(a2, bh[g][0], c, 0, 0, 0);
            c = __builtin_amdgcn_mfma_f32_16x16x32_bf16(a3, bh[g][1], c, 0, 0, 0);
            c = __builtin_amdgcn_mfma_f32_16x16x32_bf16(a0, bl[g][0], c, 0, 0, 0);
            c = __builtin_amdgcn_mfma_f32_16x16x32_bf16(a1, bl[g][1], c, 0, 0, 0);
            acc[g] = c;
        }

#pragma unroll
        for (int g = 0; g < 4; ++g) {
            float m = fmaxf(fmaxf(acc[g][0], acc[g][1]),
                            fmaxf(acc[g][2], acc[g][3]));
            bool win = (m > bb[g]);
            qv[g] = win ? acc[g] : qv[g];
            tt[g] = win ? t : tt[g];
            b2v[g] = fmaxf(b2v[g], fminf(bb[g], m));
            bb[g] = fmaxf(bb[g], m);
        }

        a0 = n0; a1 = n1; a2 = n2; a3 = n3; e2c = e2n;
    }

    // post-loop: extract index + within-quad second from the saved quad
    float ss[4];
    int   ii[4];
#pragma unroll
    for (int g = 0; g < 4; ++g) {
        float s0 = qv[g][0], s1 = qv[g][1], s2 = qv[g][2], s3 = qv[g][3];
        float M01 = fmaxf(s0, s1), L01 = fminf(s0, s1);
        float M23 = fmaxf(s2, s3), L23 = fminf(s2, s3);
        int   d01 = (s1 > s0) ? 1 : 0;
        int   d23 = (s3 > s2) ? 3 : 2;
        bool  cp  = (M23 > M01);
        float within2 = fmaxf(fminf(M01, M23), cp ? L23 : L01);
        int   dd  = cp ? d23 : d01;
        ii[g] = cbase + tt[g] * 16 + hi * 4 + dd;
        ss[g] = fmaxf(b2v[g], within2);
        // bb[g] already holds the best value
    }

    // cross-lane merge over hi (lanes c, c+16, c+32, c+48)
#pragma unroll
    for (int off = 16; off <= 32; off <<= 1) {
#pragma unroll
        for (int g = 0; g < 4; ++g) {
            float ob = __shfl_xor(bb[g], off);
            float os = __shfl_xor(ss[g], off);
            int   oi = __shfl_xor(ii[g], off);
            ss[g] = fmaxf(fmaxf(fminf(bb[g], ob), os), ss[g]);
            ii[g] = (ob > bb[g]) ? oi : ii[g];
            bb[g] = fmaxf(bb[g], ob);
        }
    }

    // cross-wave merge (4 code quarters) via LDS
    __shared__ float Lb[4][64];
    __shared__ float Ls[4][64];
    __shared__ int   Li[4][64];
    if (lane < 16) {
#pragma unroll
        for (int g = 0; g < 4; ++g) {
            Lb[w][g * 16 + lane] = bb[g];
            Ls[w][g * 16 + lane] = ss[g];
            Li[w][g * 16 + lane] = ii[g];
        }
    }
    __syncthreads();

    if (tid < 64) {
        float B = Lb[0][tid], S = Ls[0][tid];
        int   I = Li[0][tid];
#pragma unroll
        for (int w2 = 1; w2 < 4; ++w2) {
            float ob = Lb[w2][tid], os = Ls[w2][tid];
            int   oi = Li[w2][tid];
            S = fmaxf(fmaxf(fminf(B, ob), os), S);
            I = (ob > B) ? oi : I;
            B = fmaxf(B, ob);
        }
        idx[rb + tid] = I;
        if (B - S < REFINE_THR_Q) {
            int p = atomicAdd(count, 1);
            list[p] = rb + tid;
        }
    }
}

// ---------------------------------------------------------------------------
// K3: exact f64 rescan of flagged near-tie rows.
// ---------------------------------------------------------------------------
__global__ __launch_bounds__(256) void k3_refine(const float* __restrict__ z,
                                                 const float* __restrict__ emb,
                                                 const int* __restrict__ count,
                                                 const int* __restrict__ list,
                                                 int* __restrict__ idx) {
    __shared__ double sv[256];
    __shared__ int    sx[256];
    int tid = threadIdx.x;
    int n = *count;
    for (int g = blockIdx.x; g < n; g += gridDim.x) {
        int row = list[g];
        const float4* zr4 = (const float4*)(z + (size_t)row * LD);
        float4 zv[16];
#pragma unroll
        for (int q = 0; q < 16; ++q) zv[q] = zr4[q];

        double best = 1.0e300;
        int bi = NEMB;
#pragma unroll 2
        for (int c = 0; c < 8; ++c) {
            int k = tid * 8 + c;
            const float4* er = (const float4*)(emb + (size_t)k * LD);
            double d0 = 0.0, d1 = 0.0, d2 = 0.0, d3 = 0.0;
#pragma unroll
            for (int q = 0; q < 16; ++q) {
                float4 e4 = er[q];
                double tx = (double)zv[q].x - (double)e4.x;
                double ty = (double)zv[q].y - (double)e4.y;
                double tz = (double)zv[q].z - (double)e4.z;
                double tw = (double)zv[q].w - (double)e4.w;
                d0 += tx * tx; d1 += ty * ty; d2 += tz * tz; d3 += tw * tw;
            }
            double d = (d0 + d1) + (d2 + d3);
            if (d < best) { best = d; bi = k; }
        }
        sv[tid] = best; sx[tid] = bi;
        __syncthreads();
        for (int s = 128; s > 0; s >>= 1) {
            if (tid < s) {
                if (sv[tid + s] < sv[tid] ||
                    (sv[tid + s] == sv[tid] && sx[tid + s] < sx[tid])) {
                    sv[tid] = sv[tid + s]; sx[tid] = sx[tid + s];
                }
            }
            __syncthreads();
        }
        if (tid == 0) idx[row] = sx[0];
        __syncthreads();
    }
}

// ---------------------------------------------------------------------------
// K4b: hd = relu(emb[idx] @ dec_w1 + dec_b1); gathered rows staged in LDS.
// ---------------------------------------------------------------------------
__global__ __launch_bounds__(512, 4) void k4b_dec1(const int* __restrict__ idx,
                                                   const float* __restrict__ emb,
                                                   const float* __restrict__ w1,
                                                   const float* __restrict__ b1,
                                                   float* __restrict__ hdOut) {
    __shared__ float w1s[LD * HDIM];   // 16 KB
    __shared__ float zqs[64 * 64];     // 16 KB
    int tid = threadIdx.x;
    {
        const float4* src = (const float4*)w1;
        float4* dst = (float4*)w1s;
        dst[tid] = src[tid];
        dst[tid + 512] = src[tid + 512];
    }
    int r0 = blockIdx.x * 64;
    {
        float4* dst = (float4*)zqs;
#pragma unroll
        for (int t = 0; t < 2; ++t) {
            int f = tid + 512 * t;
            int r = f >> 4, q = f & 15;
            int ix = idx[r0 + r];
            dst[f] = *(const float4*)(emb + (size_t)ix * LD + q * 4);
        }
    }
    __syncthreads();

    int lane = tid & 63;
    int w = tid >> 6;
    const float* zb = &zqs[(w * 8) * 64];

    float acc[8];
#pragma unroll
    for (int r = 0; r < 8; ++r) acc[r] = 0.f;

    for (int j0 = 0; j0 < LD; j0 += 8) {
        float wf[8];
#pragma unroll
        for (int jj = 0; jj < 8; ++jj) wf[jj] = w1s[(j0 + jj) * HDIM + lane];
#pragma unroll
        for (int r = 0; r < 8; ++r) {
            const float* zr = zb + r * 64 + j0;
            float4 za = *(const float4*)zr;
            float4 zc = *(const float4*)(zr + 4);
            acc[r] += za.x * wf[0] + za.y * wf[1] + za.z * wf[2] + za.w * wf[3]
                    + zc.x * wf[4] + zc.y * wf[5] + zc.z * wf[6] + zc.w * wf[7];
        }
    }
    float bb = b1[lane];
#pragma unroll
    for (int r = 0; r < 8; ++r) {
        float h = acc[r] + bb;
        hdOut[(size_t)(r0 + w * 8 + r) * HDIM + lane] = fmaxf(h, 0.f);
    }
}

// ---------------------------------------------------------------------------
// K4c: x_recon = hd @ dec_w2 + dec_b2. ct-split, 32KB LDS, 256 thr (proven).
// ---------------------------------------------------------------------------
__global__ __launch_bounds__(256) void k4c_dec2(const float* __restrict__ hd,
                                                const float* __restrict__ w2,
                                                const float* __restrict__ b2,
                                                float* __restrict__ out) {
    __shared__ float w2s[64 * 64];   // 16 KB  [k][c]
    __shared__ float hds[64 * 64];   // 16 KB  [r][k]
    int tid = threadIdx.x;
    int rb  = blockIdx.x >> 2;
    int ct  = blockIdx.x & 3;
    int r0  = rb * 64;

    {
#pragma unroll
        for (int t = 0; t < 4; ++t) {
            int f = tid + 256 * t;
            int j = f >> 4, q = f & 15;
            *(float4*)&w2s[j * 64 + q * 4] =
                *(const float4*)(w2 + (size_t)j * SD + ct * 64 + q * 4);
        }
        const float4* src = (const float4*)(hd + (size_t)r0 * HDIM);
        float4* dst = (float4*)hds;
#pragma unroll
        for (int t = 0; t < 4; ++t) dst[tid + 256 * t] = src[tid + 256 * t];
    }
    __syncthreads();

    int lane = tid & 63;
    int w = tid >> 6;
    const float* hb = &hds[(w * 16) * 64];

    float acc[16];
#pragma unroll
    for (int r = 0; r < 16; ++r) acc[r] = 0.f;

    for (int j0 = 0; j0 < HDIM; j0 += 8) {
        float wf[8];
#pragma unroll
        for (int jj = 0; jj < 8; ++jj) wf[jj] = w2s[(j0 + jj) * 64 + lane];
#pragma unroll
        for (int r = 0; r < 16; ++r) {
            const float* hr = hb + r * 64 + j0;
            float4 ha = *(const float4*)hr;
            float4 hc = *(const float4*)(hr + 4);
            acc[r] += ha.x * wf[0] + ha.y * wf[1] + ha.z * wf[2] + ha.w * wf[3]
                    + hc.x * wf[4] + hc.y * wf[5] + hc.z * wf[6] + hc.w * wf[7];
        }
    }
    float bb = b2[ct * 64 + lane];
#pragma unroll
    for (int r = 0; r < 16; ++r)
        out[(size_t)(r0 + w * 16 + r) * SD + ct * 64 + lane] = acc[r] + bb;
}

// ---------------------------------------------------------------------------
// K4a: z_q = emb[idx]
// ---------------------------------------------------------------------------
__global__ __launch_bounds__(256) void k4a_gather(const int* __restrict__ idx,
                                                  const float* __restrict__ emb,
                                                  float* __restrict__ zq) {
    int g = blockIdx.x * 256 + threadIdx.x;
    int row = g >> 2;
    int q = g & 3;
    int ix = idx[row];
    const float4* src = (const float4*)(emb + (size_t)ix * LD) + q * 4;
    float4* dst = (float4*)(zq + (size_t)row * LD) + q * 4;
    dst[0] = src[0]; dst[1] = src[1]; dst[2] = src[2]; dst[3] = src[3];
}

// ---------------------------------------------------------------------------
extern "C" void kernel_launch(void* const* d_in, const int* in_sizes, int n_in,
                              void* d_out, int out_size, void* d_ws, size_t ws_size,
                              hipStream_t stream) {
    const float* x   = (const float*)d_in[0];
    const float* ew1 = (const float*)d_in[1];
    const float* eb1 = (const float*)d_in[2];
    const float* ew2 = (const float*)d_in[3];
    const float* eb2 = (const float*)d_in[4];
    const float* emb = (const float*)d_in[5];
    const float* dw1 = (const float*)d_in[6];
    const float* db1 = (const float*)d_in[7];
    const float* dw2 = (const float*)d_in[8];
    const float* db2 = (const float*)d_in[9];

    float* out  = (float*)d_out;
    float* xrec = out;                               // [B,256] (written LAST)
    float* zE   = out + (size_t)BATCH * SD;          // [B,64]
    float* zQ   = zE + (size_t)BATCH * LD;           // [B,64]; h/hd scratch

    // transient scratch inside the x_recon region (free until k4c):
    char* xb = (char*)xrec;
    unsigned short* zh  = (unsigned short*)xb;                        // 4 MB
    unsigned short* zl  = (unsigned short*)(xb + (4u << 20));         // 4 MB
    unsigned short* eh  = (unsigned short*)(xb + (8u << 20));         // 256 KB
    unsigned short* el  = (unsigned short*)(xb + (8u << 20) + (NEMB * LD * 2)); // 256 KB
    float*          e2q = (float*)(xb + (9u << 20));                  // 8 KB

    char* ws = (char*)d_ws;
    int*  count = (int*)ws;                                   // 4 B
    int*  idxA  = (int*)(ws + 16384);                         // 128 KB
    int*  list  = (int*)(ws + 16384 + (size_t)BATCH * 4);     // 128 KB

    hipLaunchKernelGGL(k0_prep,   dim3(NEMB / 256),  dim3(256), 0, stream, emb, e2q, eh, el, count);
    hipLaunchKernelGGL(k1a_enc1,  dim3(BATCH / 64),  dim3(512), 0, stream, x, ew1, eb1, zQ);
    hipLaunchKernelGGL(k1b_enc2,  dim3(BATCH / 64),  dim3(512), 0, stream, zQ, ew2, eb2, zE, zh, zl);
    hipLaunchKernelGGL(k2_mfma,   dim3(BATCH / 64),  dim3(256), 0, stream, zh, zl, eh, el, e2q, idxA, list, count);
    hipLaunchKernelGGL(k3_refine, dim3(128),         dim3(256), 0, stream, zE, emb, count, list, idxA);
    hipLaunchKernelGGL(k4b_dec1,  dim3(BATCH / 64),  dim3(512), 0, stream, idxA, emb, dw1, db1, zQ);
    hipLaunchKernelGGL(k4c_dec2,  dim3(BATCH / 64 * 4), dim3(256), 0, stream, zQ, dw2, db2, xrec);
    hipLaunchKernelGGL(k4a_gather, dim3(BATCH * 4 / 256), dim3(256), 0, stream, idxA, emb, zQ);
}

// Round 9
// 135.454 us; speedup vs baseline: 1.3326x; 1.1220x over previous
//
#include <hip/hip_runtime.h>

#define BATCH   32768
#define SD      256
#define LD      64
#define HDIM    64
#define NEMB    2048
#define REFINE_THR_Q 5e-4f   // gap in q-units; s-gap = 2*q-gap -> 1e-3 effective

typedef short  short8 __attribute__((ext_vector_type(8)));
typedef float  f32x4  __attribute__((ext_vector_type(4)));

__device__ __forceinline__ unsigned short f2bf(float f) {
    unsigned int u = __float_as_uint(f);
    u = (u + 0x7FFFu + ((u >> 16) & 1u)) >> 16;
    return (unsigned short)u;
}
__device__ __forceinline__ float bf2f(unsigned short h) {
    return __uint_as_float(((unsigned int)h) << 16);
}

// ---------------------------------------------------------------------------
// K0: e2q[k] = -0.5*||emb[k]||^2, bf16 split eh/el, zero refine counter.
// ---------------------------------------------------------------------------
__global__ __launch_bounds__(256) void k0_prep(const float* __restrict__ emb,
                                               float* __restrict__ e2q,
                                               unsigned short* __restrict__ eh,
                                               unsigned short* __restrict__ el,
                                               int* __restrict__ count) {
    int k = blockIdx.x * 256 + threadIdx.x;
    if (k == 0) *count = 0;
    const float* er = emb + (size_t)k * LD;
    unsigned short hrow[LD], lrow[LD];
    float s = 0.f;
#pragma unroll
    for (int q = 0; q < LD; ++q) {
        float v = er[q];
        s += v * v;
        unsigned short h = f2bf(v);
        hrow[q] = h;
        lrow[q] = f2bf(v - bf2f(h));
    }
    e2q[k] = -0.5f * s;
    short8* dh = (short8*)(eh + (size_t)k * LD);
    short8* dl = (short8*)(el + (size_t)k * LD);
#pragma unroll
    for (int q = 0; q < 8; ++q) {
        dh[q] = *(short8*)&hrow[q * 8];
        dl[q] = *(short8*)&lrow[q * 8];
    }
}

// ---------------------------------------------------------------------------
// ENC (fused k1a+k1b): z_e = (relu(x@w1+b1))@w2+b2, + bf16 split zh/zl.
// Phase 1: proven k1a body (w1 64KB LDS, x dbuf 16KB). h -> LDS (aliases
// dead w1s). w2 -> LDS (aliases dead w1s). Phase 2: proven k1b body.
// 80KB LDS, 512 thr -> 2 blocks/CU, 16 waves/CU. h never touches global.
// ---------------------------------------------------------------------------
__global__ __launch_bounds__(512, 4) void k_enc(const float* __restrict__ x,
                                                const float* __restrict__ w1,
                                                const float* __restrict__ b1,
                                                const float* __restrict__ w2,
                                                const float* __restrict__ b2,
                                                float* __restrict__ zOut,
                                                unsigned short* __restrict__ zh,
                                                unsigned short* __restrict__ zl) {
    __shared__ float smem[20480];          // 80 KB
    float* w1s = smem;                     // [0,16384) floats
    float* xs  = smem + 16384;             // [16384,20480) = xs[2][2048]
    int tid = threadIdx.x;
    {
        const float4* src = (const float4*)w1;
        float4* dst = (float4*)w1s;
#pragma unroll
        for (int t = 0; t < 8; ++t) dst[tid + 512 * t] = src[tid + 512 * t];
    }
    int r0 = blockIdx.x * 64;
    int sr = tid >> 3;
    int sq = tid & 7;
    const float* xrow = x + (size_t)(r0 + sr) * SD + sq * 4;
    *(float4*)&xs[sr * 32 + sq * 4] = *(const float4*)xrow;
    __syncthreads();

    int lane = tid & 63;
    int w = tid >> 6;
    float acc[8];
#pragma unroll
    for (int r = 0; r < 8; ++r) acc[r] = 0.f;

    for (int c = 0; c < 8; ++c) {
        float4 nv;
        if (c < 7) nv = *(const float4*)(xrow + (c + 1) * 32);
        const float* xb = &xs[(c & 1) * 2048 + (w * 8) * 32];
        int kb = c * 32;
#pragma unroll
        for (int i0 = 0; i0 < 32; i0 += 8) {
            float wf[8];
#pragma unroll
            for (int jj = 0; jj < 8; ++jj) wf[jj] = w1s[(kb + i0 + jj) * HDIM + lane];
#pragma unroll
            for (int r = 0; r < 8; ++r) {
                const float* xr = xb + r * 32 + i0;              // LDS broadcast
                float4 xa = *(const float4*)xr;
                float4 xc = *(const float4*)(xr + 4);
                acc[r] += xa.x * wf[0] + xa.y * wf[1] + xa.z * wf[2] + xa.w * wf[3]
                        + xc.x * wf[4] + xc.y * wf[5] + xc.z * wf[6] + xc.w * wf[7];
            }
        }
        __syncthreads();
        if (c < 7) *(float4*)&xs[((c + 1) & 1) * 2048 + sr * 32 + sq * 4] = nv;
        __syncthreads();
    }

    // phase 1 -> phase 2 handoff: w1s is dead; alias h (16KB) + w2 (16KB)
    float* hs  = smem;          // [0,4096)
    float* w2s = smem + 4096;   // [4096,8192)
    float bb1 = b1[lane];
#pragma unroll
    for (int r = 0; r < 8; ++r)
        hs[(w * 8 + r) * 64 + lane] = fmaxf(acc[r] + bb1, 0.f);
    {
        const float4* src = (const float4*)w2;
        float4* dst = (float4*)w2s;
        dst[tid] = src[tid];
        dst[tid + 512] = src[tid + 512];
    }
    __syncthreads();

    const float* hb = &hs[(w * 8) * 64];
    float ac2[8];
#pragma unroll
    for (int r = 0; r < 8; ++r) ac2[r] = 0.f;

    for (int j0 = 0; j0 < HDIM; j0 += 8) {
        float wf[8];
#pragma unroll
        for (int jj = 0; jj < 8; ++jj) wf[jj] = w2s[(j0 + jj) * LD + lane];
#pragma unroll
        for (int r = 0; r < 8; ++r) {
            const float* hr = hb + r * 64 + j0;                  // LDS broadcast
            float4 ha = *(const float4*)hr;
            float4 hc = *(const float4*)(hr + 4);
            ac2[r] += ha.x * wf[0] + ha.y * wf[1] + ha.z * wf[2] + ha.w * wf[3]
                    + hc.x * wf[4] + hc.y * wf[5] + hc.z * wf[6] + hc.w * wf[7];
        }
    }
    float bb2 = b2[lane];
#pragma unroll
    for (int r = 0; r < 8; ++r) {
        float z = ac2[r] + bb2;
        size_t o = (size_t)(r0 + w * 8 + r) * LD + lane;
        zOut[o] = z;
        unsigned short h = f2bf(z);
        zh[o] = h;
        zl[o] = f2bf(z - bf2f(h));
    }
}

// ---------------------------------------------------------------------------
// K2: MFMA split-bf16 screen, max-form, slim tracker, TRUE 3-deep prefetch
// (three named register sets A/B/C live simultaneously -> compiler cannot
// collapse them; every load has ~2 tile-computes of latency cover).
// R5 geometry: 512 blocks x 256 thr (4 waves), 64 rows, wave = 512 codes.
// ---------------------------------------------------------------------------
#define K2_LOAD(P, t) do {                                                  \
    const unsigned short* ph_ = ehp + (size_t)(t) * 16 * LD;                \
    const unsigned short* pl_ = elp + (size_t)(t) * 16 * LD;                \
    P##a0 = *(const short8*)(ph_);                                          \
    P##a1 = *(const short8*)(ph_ + 32);                                     \
    P##a2 = *(const short8*)(pl_);                                          \
    P##a3 = *(const short8*)(pl_ + 32);                                     \
    P##e2 = *(const f32x4*)(e2q + cbase + (t) * 16 + hi * 4);               \
} while (0)

#define K2_COMP(P, t) do {                                                  \
    f32x4 acc_[4];                                                          \
    _Pragma("unroll")                                                       \
    for (int g = 0; g < 4; ++g) {                                           \
        f32x4 c_;                                                           \
        c_ = __builtin_amdgcn_mfma_f32_16x16x32_bf16(P##a0, bh[g][0], P##e2, 0, 0, 0); \
        c_ = __builtin_amdgcn_mfma_f32_16x16x32_bf16(P##a1, bh[g][1], c_, 0, 0, 0);    \
        c_ = __builtin_amdgcn_mfma_f32_16x16x32_bf16(P##a2, bh[g][0], c_, 0, 0, 0);    \
        c_ = __builtin_amdgcn_mfma_f32_16x16x32_bf16(P##a3, bh[g][1], c_, 0, 0, 0);    \
        c_ = __builtin_amdgcn_mfma_f32_16x16x32_bf16(P##a0, bl[g][0], c_, 0, 0, 0);    \
        c_ = __builtin_amdgcn_mfma_f32_16x16x32_bf16(P##a1, bl[g][1], c_, 0, 0, 0);    \
        acc_[g] = c_;                                                       \
    }                                                                       \
    _Pragma("unroll")                                                       \
    for (int g = 0; g < 4; ++g) {                                           \
        float m_ = fmaxf(fmaxf(acc_[g][0], acc_[g][1]),                     \
                         fmaxf(acc_[g][2], acc_[g][3]));                    \
        bool win_ = (m_ > bb[g]);                                           \
        qv[g] = win_ ? acc_[g] : qv[g];                                     \
        tt[g] = win_ ? (t) : tt[g];                                         \
        b2v[g] = fmaxf(b2v[g], fminf(bb[g], m_));                           \
        bb[g] = fmaxf(bb[g], m_);                                           \
    }                                                                       \
} while (0)

__global__ __launch_bounds__(256, 2) void k2_mfma(const unsigned short* __restrict__ zh,
                                                  const unsigned short* __restrict__ zl,
                                                  const unsigned short* __restrict__ eh,
                                                  const unsigned short* __restrict__ el,
                                                  const float* __restrict__ e2q,
                                                  int* __restrict__ idx,
                                                  int* __restrict__ list,
                                                  int* __restrict__ count) {
    int tid  = threadIdx.x;
    int lane = tid & 63;
    int w    = tid >> 6;           // wave -> code quarter
    int rb   = blockIdx.x * 64;
    int lo   = lane & 15;
    int hi   = lane >> 4;

    short8 bh[4][2], bl[4][2];
#pragma unroll
    for (int g = 0; g < 4; ++g) {
        size_t zo = (size_t)(rb + g * 16 + lo) * LD + hi * 8;
        bh[g][0] = *(const short8*)(zh + zo);
        bh[g][1] = *(const short8*)(zh + zo + 32);
        bl[g][0] = *(const short8*)(zl + zo);
        bl[g][1] = *(const short8*)(zl + zo + 32);
    }

    float bb[4], b2v[4];
    f32x4 qv[4];
    int   tt[4];
#pragma unroll
    for (int g = 0; g < 4; ++g) {
        bb[g] = -3.0e38f; b2v[g] = -3.0e38f; tt[g] = 0;
        qv[g][0] = qv[g][1] = qv[g][2] = qv[g][3] = -3.0e38f;
    }

    const int cbase = w * (NEMB / 4);
    const unsigned short* ehp = eh + (size_t)(cbase + lo) * LD + hi * 8;
    const unsigned short* elp = el + (size_t)(cbase + lo) * LD + hi * 8;

    short8 Aa0, Aa1, Aa2, Aa3; f32x4 Ae2;
    short8 Ba0, Ba1, Ba2, Ba3; f32x4 Be2;
    short8 Ca0, Ca1, Ca2, Ca3; f32x4 Ce2;

    K2_LOAD(A, 0);
    K2_LOAD(B, 1);
    K2_LOAD(C, 2);

    // steady state: 9 iterations cover tiles 0..26, loads 3..29
    for (int tb = 0; tb < 27; tb += 3) {
        K2_COMP(A, tb);     K2_LOAD(A, tb + 3);
        K2_COMP(B, tb + 1); K2_LOAD(B, tb + 4);
        K2_COMP(C, tb + 2); K2_LOAD(C, tb + 5);
    }
    // peel: tiles 27..29 (loads 30,31), then tail 30,31
    K2_COMP(A, 27); K2_LOAD(A, 30);
    K2_COMP(B, 28); K2_LOAD(B, 31);
    K2_COMP(C, 29);
    K2_COMP(A, 30);
    K2_COMP(B, 31);

    // post-loop: extract index + within-quad second from the saved quad
    float ss[4];
    int   ii[4];
#pragma unroll
    for (int g = 0; g < 4; ++g) {
        float s0 = qv[g][0], s1 = qv[g][1], s2 = qv[g][2], s3 = qv[g][3];
        float M01 = fmaxf(s0, s1), L01 = fminf(s0, s1);
        float M23 = fmaxf(s2, s3), L23 = fminf(s2, s3);
        int   d01 = (s1 > s0) ? 1 : 0;
        int   d23 = (s3 > s2) ? 3 : 2;
        bool  cp  = (M23 > M01);
        float within2 = fmaxf(fminf(M01, M23), cp ? L23 : L01);
        int   dd  = cp ? d23 : d01;
        ii[g] = cbase + tt[g] * 16 + hi * 4 + dd;
        ss[g] = fmaxf(b2v[g], within2);
    }

#pragma unroll
    for (int off = 16; off <= 32; off <<= 1) {
#pragma unroll
        for (int g = 0; g < 4; ++g) {
            float ob = __shfl_xor(bb[g], off);
            float os = __shfl_xor(ss[g], off);
            int   oi = __shfl_xor(ii[g], off);
            ss[g] = fmaxf(fmaxf(fminf(bb[g], ob), os), ss[g]);
            ii[g] = (ob > bb[g]) ? oi : ii[g];
            bb[g] = fmaxf(bb[g], ob);
        }
    }

    __shared__ float Lb[4][64];
    __shared__ float Ls[4][64];
    __shared__ int   Li[4][64];
    if (lane < 16) {
#pragma unroll
        for (int g = 0; g < 4; ++g) {
            Lb[w][g * 16 + lane] = bb[g];
            Ls[w][g * 16 + lane] = ss[g];
            Li[w][g * 16 + lane] = ii[g];
        }
    }
    __syncthreads();

    if (tid < 64) {
        float B = Lb[0][tid], S = Ls[0][tid];
        int   I = Li[0][tid];
#pragma unroll
        for (int w2 = 1; w2 < 4; ++w2) {
            float ob = Lb[w2][tid], os = Ls[w2][tid];
            int   oi = Li[w2][tid];
            S = fmaxf(fmaxf(fminf(B, ob), os), S);
            I = (ob > B) ? oi : I;
            B = fmaxf(B, ob);
        }
        idx[rb + tid] = I;
        if (B - S < REFINE_THR_Q) {
            int p = atomicAdd(count, 1);
            list[p] = rb + tid;
        }
    }
}

// ---------------------------------------------------------------------------
// K3: exact f64 rescan of flagged near-tie rows.
// ---------------------------------------------------------------------------
__global__ __launch_bounds__(256) void k3_refine(const float* __restrict__ z,
                                                 const float* __restrict__ emb,
                                                 const int* __restrict__ count,
                                                 const int* __restrict__ list,
                                                 int* __restrict__ idx) {
    __shared__ double sv[256];
    __shared__ int    sx[256];
    int tid = threadIdx.x;
    int n = *count;
    for (int g = blockIdx.x; g < n; g += gridDim.x) {
        int row = list[g];
        const float4* zr4 = (const float4*)(z + (size_t)row * LD);
        float4 zv[16];
#pragma unroll
        for (int q = 0; q < 16; ++q) zv[q] = zr4[q];

        double best = 1.0e300;
        int bi = NEMB;
#pragma unroll 2
        for (int c = 0; c < 8; ++c) {
            int k = tid * 8 + c;
            const float4* er = (const float4*)(emb + (size_t)k * LD);
            double d0 = 0.0, d1 = 0.0, d2 = 0.0, d3 = 0.0;
#pragma unroll
            for (int q = 0; q < 16; ++q) {
                float4 e4 = er[q];
                double tx = (double)zv[q].x - (double)e4.x;
                double ty = (double)zv[q].y - (double)e4.y;
                double tz = (double)zv[q].z - (double)e4.z;
                double tw = (double)zv[q].w - (double)e4.w;
                d0 += tx * tx; d1 += ty * ty; d2 += tz * tz; d3 += tw * tw;
            }
            double d = (d0 + d1) + (d2 + d3);
            if (d < best) { best = d; bi = k; }
        }
        sv[tid] = best; sx[tid] = bi;
        __syncthreads();
        for (int s = 128; s > 0; s >>= 1) {
            if (tid < s) {
                if (sv[tid + s] < sv[tid] ||
                    (sv[tid + s] == sv[tid] && sx[tid + s] < sx[tid])) {
                    sv[tid] = sv[tid + s]; sx[tid] = sx[tid + s];
                }
            }
            __syncthreads();
        }
        if (tid == 0) idx[row] = sx[0];
        __syncthreads();
    }
}

// ---------------------------------------------------------------------------
// DEC (fused k4b+k4c+k4a): z_q gather -> LDS (+global write), hd in LDS only,
// then 4 sequential 64-col tiles of x_recon with 16KB w2-slice reloads.
// 48KB LDS, 512 thr. hd never touches global; one launch instead of three.
// ---------------------------------------------------------------------------
__global__ __launch_bounds__(512, 4) void k_dec(const int* __restrict__ idx,
                                                const float* __restrict__ emb,
                                                const float* __restrict__ w1,
                                                const float* __restrict__ b1,
                                                const float* __restrict__ w2,
                                                const float* __restrict__ b2,
                                                float* __restrict__ xrec,
                                                float* __restrict__ zq) {
    __shared__ float smem[12288];   // 48 KB
    float* w1s = smem;              // [0,4096)
    float* zqs = smem + 4096;       // [4096,8192)
    float* hds = smem + 8192;       // [8192,12288)
    int tid = threadIdx.x;
    int r0 = blockIdx.x * 64;
    {
        const float4* src = (const float4*)w1;
        float4* dst = (float4*)w1s;
        dst[tid] = src[tid];
        dst[tid + 512] = src[tid + 512];
    }
    {
        float4* dst = (float4*)zqs;
#pragma unroll
        for (int t = 0; t < 2; ++t) {
            int f = tid + 512 * t;
            int r = f >> 4, q = f & 15;
            int ix = idx[r0 + r];
            dst[f] = *(const float4*)(emb + (size_t)ix * LD + q * 4);
        }
    }
    __syncthreads();
    {   // write z_q (coalesced from LDS)
        const float4* s = (const float4*)zqs;
        float4* d = (float4*)(zq + (size_t)r0 * LD);
        d[tid] = s[tid];
        d[tid + 512] = s[tid + 512];
    }

    int lane = tid & 63;
    int w = tid >> 6;
    const float* zb = &zqs[(w * 8) * 64];

    float acc[8];
#pragma unroll
    for (int r = 0; r < 8; ++r) acc[r] = 0.f;

    for (int j0 = 0; j0 < LD; j0 += 8) {
        float wf[8];
#pragma unroll
        for (int jj = 0; jj < 8; ++jj) wf[jj] = w1s[(j0 + jj) * HDIM + lane];
#pragma unroll
        for (int r = 0; r < 8; ++r) {
            const float* zr = zb + r * 64 + j0;                 // LDS broadcast
            float4 za = *(const float4*)zr;
            float4 zc = *(const float4*)(zr + 4);
            acc[r] += za.x * wf[0] + za.y * wf[1] + za.z * wf[2] + za.w * wf[3]
                    + zc.x * wf[4] + zc.y * wf[5] + zc.z * wf[6] + zc.w * wf[7];
        }
    }
    float bb1 = b1[lane];
#pragma unroll
    for (int r = 0; r < 8; ++r)
        hds[(w * 8 + r) * 64 + lane] = fmaxf(acc[r] + bb1, 0.f);
    __syncthreads();

    // phase B: 4 column-tiles, w2 slice reloaded into dead w1s region
    float* w2s = smem;   // [0,4096)
    for (int ct = 0; ct < 4; ++ct) {
#pragma unroll
        for (int t = 0; t < 2; ++t) {
            int f = tid + 512 * t;
            int j = f >> 4, q = f & 15;
            *(float4*)&w2s[j * 64 + q * 4] =
                *(const float4*)(w2 + (size_t)j * SD + ct * 64 + q * 4);
        }
        __syncthreads();

        float a2[8];
#pragma unroll
        for (int r = 0; r < 8; ++r) a2[r] = 0.f;
        const float* hb = &hds[(w * 8) * 64];
        for (int j0 = 0; j0 < HDIM; j0 += 8) {
            float wf[8];
#pragma unroll
            for (int jj = 0; jj < 8; ++jj) wf[jj] = w2s[(j0 + jj) * 64 + lane];
#pragma unroll
            for (int r = 0; r < 8; ++r) {
                const float* hr = hb + r * 64 + j0;             // LDS broadcast
                float4 ha = *(const float4*)hr;
                float4 hc = *(const float4*)(hr + 4);
                a2[r] += ha.x * wf[0] + ha.y * wf[1] + ha.z * wf[2] + ha.w * wf[3]
                       + hc.x * wf[4] + hc.y * wf[5] + hc.z * wf[6] + hc.w * wf[7];
            }
        }
        float bbo = b2[ct * 64 + lane];
#pragma unroll
        for (int r = 0; r < 8; ++r)
            xrec[(size_t)(r0 + w * 8 + r) * SD + ct * 64 + lane] = a2[r] + bbo;
        __syncthreads();
    }
}

// ---------------------------------------------------------------------------
extern "C" void kernel_launch(void* const* d_in, const int* in_sizes, int n_in,
                              void* d_out, int out_size, void* d_ws, size_t ws_size,
                              hipStream_t stream) {
    const float* x   = (const float*)d_in[0];
    const float* ew1 = (const float*)d_in[1];
    const float* eb1 = (const float*)d_in[2];
    const float* ew2 = (const float*)d_in[3];
    const float* eb2 = (const float*)d_in[4];
    const float* emb = (const float*)d_in[5];
    const float* dw1 = (const float*)d_in[6];
    const float* db1 = (const float*)d_in[7];
    const float* dw2 = (const float*)d_in[8];
    const float* db2 = (const float*)d_in[9];

    float* out  = (float*)d_out;
    float* xrec = out;                               // [B,256] (written LAST)
    float* zE   = out + (size_t)BATCH * SD;          // [B,64]
    float* zQ   = zE + (size_t)BATCH * LD;           // [B,64]

    // transient scratch inside the x_recon region (dead once k_dec writes):
    char* xb = (char*)xrec;
    unsigned short* zh  = (unsigned short*)xb;                        // 4 MB
    unsigned short* zl  = (unsigned short*)(xb + (4u << 20));         // 4 MB
    unsigned short* eh  = (unsigned short*)(xb + (8u << 20));         // 256 KB
    unsigned short* el  = (unsigned short*)(xb + (8u << 20) + (NEMB * LD * 2)); // 256 KB
    float*          e2q = (float*)(xb + (9u << 20));                  // 8 KB

    char* ws = (char*)d_ws;
    int*  count = (int*)ws;                                   // 4 B
    int*  idxA  = (int*)(ws + 16384);                         // 128 KB
    int*  list  = (int*)(ws + 16384 + (size_t)BATCH * 4);     // 128 KB

    hipLaunchKernelGGL(k0_prep,   dim3(NEMB / 256), dim3(256), 0, stream, emb, e2q, eh, el, count);
    hipLaunchKernelGGL(k_enc,     dim3(BATCH / 64), dim3(512), 0, stream, x, ew1, eb1, ew2, eb2, zE, zh, zl);
    hipLaunchKernelGGL(k2_mfma,   dim3(BATCH / 64), dim3(256), 0, stream, zh, zl, eh, el, e2q, idxA, list, count);
    hipLaunchKernelGGL(k3_refine, dim3(128),        dim3(256), 0, stream, zE, emb, count, list, idxA);
    hipLaunchKernelGGL(k_dec,     dim3(BATCH / 64), dim3(512), 0, stream, idxA, emb, dw1, db1, dw2, db2, xrec, zQ);
}